// Round 10
// baseline (242.862 us; speedup 1.0000x reference)
//
#include <hip/hip_runtime.h>
#include <float.h>

#define Bn 2
#define Nn 8192
#define Rr 2048
#define Kk 16
#define CIN 64
#define CL 16
#define COUT 128
#define K2c 256
#define GT (Bn*Rr)      // 4096 groups
#define FD (CL+CIN)     // 80
#define KC (Kk*FD)      // 1280
#define MG 8            // mlp groups per block

// ---------------- prep: weight transposes / permute + pts4 packing ----------------
__global__ __launch_bounds__(256) void prep_kernel(
    const float* __restrict__ t1_w, const float* __restrict__ t2_w,
    const float* __restrict__ t3_w, const float* __restrict__ conv_w,
    const float* __restrict__ points,
    float* __restrict__ t1t, float* __restrict__ t2t,
    float* __restrict__ t3t, float* __restrict__ wp,
    float4* __restrict__ pts4)
{
  int i = blockIdx.x * 256 + threadIdx.x;
  if (i < K2c*48) { int j = i / 48, k = i - j*48; t1t[k*K2c + j] = t1_w[i]; }
  if (i < K2c*K2c) { int j = i >> 8, k = i & 255; t2t[k*K2c + j] = t2_w[i]; t3t[k*K2c + j] = t3_w[i]; }
  if (i < COUT*KC) {
    int o = i / KC, ck = i - o*KC;
    int c = ck >> 4, k = ck & 15;
    wp[(k*FD + c)*COUT + o] = conv_w[i];
  }
  if (i < Bn*Nn) {
    float x = points[i*3+0], y = points[i*3+1], z = points[i*3+2];
    // numpy order: sq = (x*x + y*y) + z*z, muls materialized then summed
    float sq = __fadd_rn(__fadd_rn(__fmul_rn(x,x), __fmul_rn(y,y)), __fmul_rn(z,z));
    pts4[i] = make_float4(x, y, z, sq);
  }
}

// ---------------- knn v4: 2 queries/wave, two-pass value-scan + tau + collect ----------------
// One candidate load serves BOTH queries (halves load-pipe work). Selection
// semantics identical to v3: value-only top-3 (med3/min), tau >= true 17th
// smallest, pass-2 superset collection with bit-identical d2, exact u64
// lexicographic top-17 extraction (stable top_k order).
__global__ __launch_bounds__(256) void knn_kernel(
    const float4* __restrict__ pts4, const int* __restrict__ rep_idx,
    int* __restrict__ nb_idx, float* __restrict__ p_out,
    float* __restrict__ rep_pos_out)
{
  __shared__ unsigned long long coll[4][2][128];   // 8 KB
  int t    = threadIdx.x;
  int lane = t & 63;
  int w    = t >> 6;
  int gA   = blockIdx.x * 8 + w*2;   // wave owns queries gA, gA+1 (same batch: 8 | 2048)
  int b    = gA >> 11;
  int rA   = gA & 2047;
  int nA   = rep_idx[rA];
  int nB   = rep_idx[rA + 1];
  const float4* pb4 = pts4 + (size_t)b*Nn;
  float4 QA = pb4[nA];
  float4 QB = pb4[nB];

  // ---- pass 1: per-lane top-3 VALUES for both queries ----
  float a0 = FLT_MAX, a1 = FLT_MAX, a2 = FLT_MAX;
  float b0 = FLT_MAX, b1 = FLT_MAX, b2 = FLT_MAX;
  #pragma unroll 4
  for (int j = 0; j < 128; j++) {
    float4 P = pb4[j*64 + lane];
    float dotA = __fmaf_rn(QA.z, P.z, __fmaf_rn(QA.y, P.y, __fmul_rn(QA.x, P.x)));
    float d2A  = __fsub_rn(__fadd_rn(QA.w, P.w), __fmul_rn(2.0f, dotA));
    float dotB = __fmaf_rn(QB.z, P.z, __fmaf_rn(QB.y, P.y, __fmul_rn(QB.x, P.x)));
    float d2B  = __fsub_rn(__fadd_rn(QB.w, P.w), __fmul_rn(2.0f, dotB));
    float na2 = __builtin_amdgcn_fmed3f(a1, a2, d2A);
    float na1 = __builtin_amdgcn_fmed3f(a0, a1, d2A);
    float na0 = fminf(a0, d2A);
    a0 = na0; a1 = na1; a2 = na2;
    float nb2 = __builtin_amdgcn_fmed3f(b1, b2, d2B);
    float nb1 = __builtin_amdgcn_fmed3f(b0, b1, d2B);
    float nb0 = fminf(b0, d2B);
    b0 = nb0; b1 = nb1; b2 = nb2;
  }

  // ---- tau per query: 17 rounds of wave-wide min with pop ----
  float tauA = FLT_MAX, tauB = FLT_MAX;
  for (int rnd = 0; rnd < 17; rnd++) {
    float m = a0;
    #pragma unroll
    for (int off = 1; off < 64; off <<= 1) m = fminf(m, __shfl_xor(m, off));
    if (a0 == m) { a0 = a1; a1 = a2; a2 = FLT_MAX; }
    tauA = m;
  }
  for (int rnd = 0; rnd < 17; rnd++) {
    float m = b0;
    #pragma unroll
    for (int off = 1; off < 64; off <<= 1) m = fminf(m, __shfl_xor(m, off));
    if (b0 == m) { b0 = b1; b1 = b2; b2 = FLT_MAX; }
    tauB = m;
  }

  // ---- pass 2: collect (d2, m) <= tau for both queries, ballot compaction ----
  int cntA = 0, cntB = 0;
  #pragma unroll 4
  for (int j = 0; j < 128; j++) {
    float4 P = pb4[j*64 + lane];
    float dotA = __fmaf_rn(QA.z, P.z, __fmaf_rn(QA.y, P.y, __fmul_rn(QA.x, P.x)));
    float d2A  = __fsub_rn(__fadd_rn(QA.w, P.w), __fmul_rn(2.0f, dotA));
    float dotB = __fmaf_rn(QB.z, P.z, __fmaf_rn(QB.y, P.y, __fmul_rn(QB.x, P.x)));
    float d2B  = __fsub_rn(__fadd_rn(QB.w, P.w), __fmul_rn(2.0f, dotB));
    int m = j*64 + lane;
    bool prA = (d2A <= tauA);
    unsigned long long maskA = __ballot(prA);
    if (prA) {
      int pos = cntA + (int)__popcll(maskA & ((1ull << lane) - 1ull));
      if (pos < 128) {
        unsigned f = __float_as_uint(d2A);
        unsigned mono = f ^ ((unsigned)((int)f >> 31) | 0x80000000u);
        coll[w][0][pos] = ((unsigned long long)mono << 32) | (unsigned)m;
      }
    }
    cntA += (int)__popcll(maskA);
    bool prB = (d2B <= tauB);
    unsigned long long maskB = __ballot(prB);
    if (prB) {
      int pos = cntB + (int)__popcll(maskB & ((1ull << lane) - 1ull));
      if (pos < 128) {
        unsigned f = __float_as_uint(d2B);
        unsigned mono = f ^ ((unsigned)((int)f >> 31) | 0x80000000u);
        coll[w][1][pos] = ((unsigned long long)mono << 32) | (unsigned)m;
      }
    }
    cntB += (int)__popcll(maskB);
  }
  if (cntA > 128) cntA = 128;
  if (cntB > 128) cntB = 128;

  // ---- final: exact top-17 extraction, query A then B ----
  #pragma unroll
  for (int q = 0; q < 2; q++) {
    int cnt = q ? cntB : cntA;
    int g   = gA + q;
    float qx = q ? QB.x : QA.x;
    float qy = q ? QB.y : QA.y;
    float qz = q ? QB.z : QA.z;
    unsigned long long e1 = (lane < cnt)      ? coll[w][q][lane]      : ~0ull;
    unsigned long long e2 = (lane + 64 < cnt) ? coll[w][q][lane + 64] : ~0ull;
    int out_m = 0;
    for (int rnd = 0; rnd < 17; rnd++) {
      unsigned long long myk = (e1 < e2) ? e1 : e2;
      unsigned long long kmin = myk;
      #pragma unroll
      for (int off = 1; off < 64; off <<= 1) {
        unsigned long long o = __shfl_xor(kmin, off);
        kmin = (o < kmin) ? o : kmin;
      }
      if (rnd >= 1 && lane == rnd - 1) out_m = (int)(kmin & 0xFFFFFFFFull);
      if (kmin == e1) e1 = ~0ull;
      else if (kmin == e2) e2 = ~0ull;
    }
    if (lane < 16) {
      nb_idx[g*Kk + lane] = out_m;
      float4 P = pb4[out_m];
      p_out[(g*Kk + lane)*3 + 0] = __fsub_rn(P.x, qx);
      p_out[(g*Kk + lane)*3 + 1] = __fsub_rn(P.y, qy);
      p_out[(g*Kk + lane)*3 + 2] = __fsub_rn(P.z, qz);
    }
    if (lane < 3) rep_pos_out[g*3 + lane] = (lane == 0 ? qx : (lane == 1 ? qy : qz));
  }
}

// ---------------- mlp v4: k-split waves, weights from L2, LDS for broadcasts only ----------------
__device__ __forceinline__ void fma_g(float4& a, float hv, const float4& wv) {
  a.x = fmaf(hv, wv.x, a.x);
  a.y = fmaf(hv, wv.y, a.y);
  a.z = fmaf(hv, wv.z, a.z);
  a.w = fmaf(hv, wv.w, a.w);
}

__global__ __launch_bounds__(256) void mlp_kernel(
    const float* __restrict__ p,
    const float* __restrict__ t1t, const float* __restrict__ t1_b,
    const float* __restrict__ g1v, const float* __restrict__ b1v,
    const float* __restrict__ t2t, const float* __restrict__ t2_b,
    const float* __restrict__ g2v, const float* __restrict__ b2v,
    const float* __restrict__ t3t, const float* __restrict__ t3_b,
    const float* __restrict__ g3v, const float* __restrict__ b3v,
    float* __restrict__ T_out)
{
  __shared__ float pf[48][MG];       // 1.5 KB
  __shared__ float hA[K2c][MG];      // 8 KB
  __shared__ float red[4][64][36];   // 36.9 KB padded partials
  int t = threadIdx.x;
  int w = t >> 6, l = t & 63;
  int g0 = blockIdx.x * MG;
  for (int e = t; e < MG*48; e += 256) {
    int g = e / 48, k = e - g*48;
    pf[k][g] = p[(size_t)(g0+g)*48 + k];
  }
  __syncthreads();

  float4 acc[8];   // acc[g] over cols 4l..4l+3

#define KLOOP(WSRC, KDIM, HBUF)                                        \
  {                                                                    \
    _Pragma("unroll")                                                  \
    for (int q = 0; q < 8; q++) acc[q] = make_float4(0.f,0.f,0.f,0.f); \
    float4 wb0 = *(const float4*)&WSRC[(size_t)w*K2c + 4*l];           \
    float4 wb1 = (w + 4 < KDIM) ?                                      \
        *(const float4*)&WSRC[(size_t)(w+4)*K2c + 4*l] : wb0;          \
    _Pragma("unroll 2")                                                \
    for (int k = w; k < KDIM; k += 4) {                                \
      float4 wc = wb0; wb0 = wb1;                                      \
      if (k + 8 < KDIM)                                                \
        wb1 = *(const float4*)&WSRC[(size_t)(k+8)*K2c + 4*l];          \
      float4 h0 = *(const float4*)&HBUF[k][0];                         \
      float4 h1 = *(const float4*)&HBUF[k][4];                         \
      fma_g(acc[0], h0.x, wc); fma_g(acc[1], h0.y, wc);                \
      fma_g(acc[2], h0.z, wc); fma_g(acc[3], h0.w, wc);                \
      fma_g(acc[4], h1.x, wc); fma_g(acc[5], h1.y, wc);                \
      fma_g(acc[6], h1.z, wc); fma_g(acc[7], h1.w, wc);                \
    }                                                                  \
  }

#define WRITE_RED()                                                        \
  {                                                                        \
    float4 ra, rb;                                                         \
    ra = make_float4(acc[0].x, acc[1].x, acc[2].x, acc[3].x);              \
    rb = make_float4(acc[4].x, acc[5].x, acc[6].x, acc[7].x);              \
    *(float4*)&red[w][l][0]  = ra; *(float4*)&red[w][l][4]  = rb;          \
    ra = make_float4(acc[0].y, acc[1].y, acc[2].y, acc[3].y);              \
    rb = make_float4(acc[4].y, acc[5].y, acc[6].y, acc[7].y);              \
    *(float4*)&red[w][l][8]  = ra; *(float4*)&red[w][l][12] = rb;          \
    ra = make_float4(acc[0].z, acc[1].z, acc[2].z, acc[3].z);              \
    rb = make_float4(acc[4].z, acc[5].z, acc[6].z, acc[7].z);              \
    *(float4*)&red[w][l][16] = ra; *(float4*)&red[w][l][20] = rb;          \
    ra = make_float4(acc[0].w, acc[1].w, acc[2].w, acc[3].w);              \
    rb = make_float4(acc[4].w, acc[5].w, acc[6].w, acc[7].w);              \
    *(float4*)&red[w][l][24] = ra; *(float4*)&red[w][l][28] = rb;          \
  }

#define REDUCE(SA, SB)                                                     \
  float4 SA = make_float4(0.f,0.f,0.f,0.f), SB = SA;                       \
  {                                                                        \
    int lr = t >> 2, cc = t & 3;                                           \
    _Pragma("unroll")                                                      \
    for (int ww = 0; ww < 4; ww++) {                                       \
      float4 pa = *(const float4*)&red[ww][lr][cc*8 + 0];                  \
      float4 pb = *(const float4*)&red[ww][lr][cc*8 + 4];                  \
      SA.x += pa.x; SA.y += pa.y; SA.z += pa.z; SA.w += pa.w;              \
      SB.x += pb.x; SB.y += pb.y; SB.z += pb.z; SB.w += pb.w;              \
    }                                                                      \
  }

  // ===== layer 1 (K=48), relu =====
  KLOOP(t1t, 48, pf)
  WRITE_RED()
  __syncthreads();
  {
    REDUCE(sa, sb)
    float bb = t1_b[t], gg = g1v[t], oo = b1v[t];
    float4 va, vb;
    va.x = fmaxf(fmaf(sa.x + bb, gg, oo), 0.f);
    va.y = fmaxf(fmaf(sa.y + bb, gg, oo), 0.f);
    va.z = fmaxf(fmaf(sa.z + bb, gg, oo), 0.f);
    va.w = fmaxf(fmaf(sa.w + bb, gg, oo), 0.f);
    vb.x = fmaxf(fmaf(sb.x + bb, gg, oo), 0.f);
    vb.y = fmaxf(fmaf(sb.y + bb, gg, oo), 0.f);
    vb.z = fmaxf(fmaf(sb.z + bb, gg, oo), 0.f);
    vb.w = fmaxf(fmaf(sb.w + bb, gg, oo), 0.f);
    *(float4*)&hA[t][0] = va;
    *(float4*)&hA[t][4] = vb;
  }
  __syncthreads();

  // ===== layer 2 (K=256), relu =====
  KLOOP(t2t, K2c, hA)
  __syncthreads();
  WRITE_RED()
  __syncthreads();
  {
    REDUCE(sa, sb)
    float bb = t2_b[t], gg = g2v[t], oo = b2v[t];
    float4 va, vb;
    va.x = fmaxf(fmaf(sa.x + bb, gg, oo), 0.f);
    va.y = fmaxf(fmaf(sa.y + bb, gg, oo), 0.f);
    va.z = fmaxf(fmaf(sa.z + bb, gg, oo), 0.f);
    va.w = fmaxf(fmaf(sa.w + bb, gg, oo), 0.f);
    vb.x = fmaxf(fmaf(sb.x + bb, gg, oo), 0.f);
    vb.y = fmaxf(fmaf(sb.y + bb, gg, oo), 0.f);
    vb.z = fmaxf(fmaf(sb.z + bb, gg, oo), 0.f);
    vb.w = fmaxf(fmaf(sb.w + bb, gg, oo), 0.f);
    *(float4*)&hA[t][0] = va;
    *(float4*)&hA[t][4] = vb;
  }
  __syncthreads();

  // ===== layer 3 (K=256), no relu, to global =====
  KLOOP(t3t, K2c, hA)
  WRITE_RED()
  __syncthreads();
  {
    REDUCE(sa, sb)
    float bb = t3_b[t], gg = g3v[t], oo = b3v[t];
    T_out[(size_t)(g0+0)*K2c + t] = fmaf(sa.x + bb, gg, oo);
    T_out[(size_t)(g0+1)*K2c + t] = fmaf(sa.y + bb, gg, oo);
    T_out[(size_t)(g0+2)*K2c + t] = fmaf(sa.z + bb, gg, oo);
    T_out[(size_t)(g0+3)*K2c + t] = fmaf(sa.w + bb, gg, oo);
    T_out[(size_t)(g0+4)*K2c + t] = fmaf(sb.x + bb, gg, oo);
    T_out[(size_t)(g0+5)*K2c + t] = fmaf(sb.y + bb, gg, oo);
    T_out[(size_t)(g0+6)*K2c + t] = fmaf(sb.z + bb, gg, oo);
    T_out[(size_t)(g0+7)*K2c + t] = fmaf(sb.w + bb, gg, oo);
  }
#undef KLOOP
#undef WRITE_RED
#undef REDUCE
}

// ---------------- tf (fused feat): build feat in LDS, Tf = T @ feat ----------------
__global__ __launch_bounds__(256) void tf_kernel(
    const float* __restrict__ T_in, const float* __restrict__ features,
    const float* __restrict__ p, const int* __restrict__ nb_idx,
    const float* __restrict__ lift_w, const float* __restrict__ lift_b,
    const float* __restrict__ bng, const float* __restrict__ bnb,
    float* __restrict__ Tf)
{
  __shared__ float T_s[8*K2c];    // 8 KB
  __shared__ float f_s[8*KC];     // 40 KB
  __shared__ float ps[8*48];      // 1.5 KB
  __shared__ int   idxs[128];     // 512 B
  __shared__ float lw[48], lb2[16], lg[16], lo[16];
  int t = threadIdx.x;
  int g0 = blockIdx.x * 8;
  int b = g0 / Rr;                // block never straddles batches (2048 % 8 == 0)
  for (int e = t; e < 8*K2c; e += 256) T_s[e] = T_in[(size_t)g0*K2c + e];
  for (int e = t; e < 8*48;  e += 256) ps[e]  = p[(size_t)g0*48 + e];
  if (t < 128) idxs[t] = nb_idx[g0*16 + t];
  if (t >= 128 && t < 176) lw[t-128]  = lift_w[t-128];
  if (t >= 176 && t < 192) lb2[t-176] = lift_b[t-176];
  if (t >= 192 && t < 208) lg[t-192]  = bng[t-192];
  if (t >= 208 && t < 224) lo[t-208]  = bnb[t-208];
  __syncthreads();

  // gather neighbor features: 128 rows of 64, one row per wave-instr
  {
    int wv = t >> 6, ln = t & 63;
    for (int row = wv; row < 128; row += 4) {
      int gg = row >> 4, k = row & 15;
      f_s[gg*KC + k*FD + CL + ln] = features[((size_t)b*Nn + idxs[row])*CIN + ln];
    }
  }
  // lifted BN+ReLU: 8*16*16 = 2048 elements
  for (int e = t; e < 2048; e += 256) {
    int gg = e >> 8, rem = e & 255, k = rem >> 4, c = rem & 15;
    float acc = ps[gg*48 + k*3 + 0]*lw[c*3+0] + ps[gg*48 + k*3 + 1]*lw[c*3+1]
              + ps[gg*48 + k*3 + 2]*lw[c*3+2] + lb2[c];
    acc = acc*lg[c] + lo[c];
    f_s[gg*KC + k*FD + c] = fmaxf(acc, 0.f);
  }
  __syncthreads();

  int gg = t >> 5;
  int cl = t & 31;
  for (int ci = cl; ci < FD; ci += 32) {
    float fcol[16];
    #pragma unroll
    for (int j = 0; j < 16; j++) fcol[j] = f_s[gg*KC + j*FD + ci];
    #pragma unroll
    for (int k = 0; k < 16; k++) {
      float acc = 0.f;
      #pragma unroll
      for (int j = 0; j < 16; j++) acc = fmaf(T_s[gg*K2c + k*16 + j], fcol[j], acc);
      Tf[(size_t)(g0+gg)*KC + k*FD + ci] = acc;
    }
  }
}

// ---------------- gemm: out = Tf(4096x1280) @ Wp(1280x128), split-K=4 ----------------
__global__ __launch_bounds__(256) void gemm_kernel(
    const float* __restrict__ A,    // Tf
    const float* __restrict__ Bm,   // Wp
    float* __restrict__ part)       // [4][GT][COUT]
{
  __shared__ float As[16*36];
  __shared__ float Bs[16*COUT];
  int t = threadIdx.x;
  int m0 = blockIdx.x * 32;
  int ky = blockIdx.y;
  int kbase0 = ky * (KC/4);
  float acc[4][4];
  #pragma unroll
  for (int i = 0; i < 4; i++)
    #pragma unroll
    for (int j = 0; j < 4; j++) acc[i][j] = 0.f;
  int tn = t & 31, tm = t >> 5;

  for (int kt = 0; kt < KC/4; kt += 16) {
    int kb = kbase0 + kt;
    {
      int kcol = t & 15, row = t >> 4;
      As[kcol*36 + row]      = A[(size_t)(m0+row)*KC + kb + kcol];
      As[kcol*36 + row + 16] = A[(size_t)(m0+row+16)*KC + kb + kcol];
    }
    {
      int o = t & 127, kk2 = t >> 7;
      #pragma unroll
      for (int p4 = 0; p4 < 8; p4++) {
        int kk = kk2 + p4*2;
        Bs[kk*COUT + o] = Bm[(size_t)(kb+kk)*COUT + o];
      }
    }
    __syncthreads();
    #pragma unroll
    for (int kk = 0; kk < 16; kk++) {
      float4 a4 = *(const float4*)&As[kk*36 + tm*4];
      float4 b4 = *(const float4*)&Bs[kk*COUT + tn*4];
      float av[4] = {a4.x, a4.y, a4.z, a4.w};
      float bv[4] = {b4.x, b4.y, b4.z, b4.w};
      #pragma unroll
      for (int i = 0; i < 4; i++)
        #pragma unroll
        for (int j = 0; j < 4; j++) acc[i][j] = fmaf(av[i], bv[j], acc[i][j]);
    }
    __syncthreads();
  }
  #pragma unroll
  for (int i = 0; i < 4; i++) {
    float4 v = make_float4(acc[i][0], acc[i][1], acc[i][2], acc[i][3]);
    *(float4*)&part[((size_t)ky*GT + m0 + tm*4 + i)*COUT + tn*4] = v;
  }
}

// ---------------- reduce: out = sum(part[0..3]) + bias ----------------
__global__ __launch_bounds__(256) void reduce_kernel(
    const float* __restrict__ part, const float* __restrict__ conv_b,
    float* __restrict__ outp)
{
  int i = blockIdx.x*256 + threadIdx.x;
  const float4* p0 = (const float4*)part;
  const float4* p1 = (const float4*)(part + 1*(size_t)GT*COUT);
  const float4* p2 = (const float4*)(part + 2*(size_t)GT*COUT);
  const float4* p3 = (const float4*)(part + 3*(size_t)GT*COUT);
  float4 a = p0[i], b = p1[i], c = p2[i], d = p3[i];
  float4 e = ((const float4*)conv_b)[i & 31];
  float4 rr;
  rr.x = a.x + b.x + c.x + d.x + e.x;
  rr.y = a.y + b.y + c.y + d.y + e.y;
  rr.z = a.z + b.z + c.z + d.z + e.z;
  rr.w = a.w + b.w + c.w + d.w + e.w;
  ((float4*)outp)[i] = rr;
}

extern "C" void kernel_launch(void* const* d_in, const int* in_sizes, int n_in,
                              void* d_out, int out_size, void* d_ws, size_t ws_size,
                              hipStream_t stream) {
  const float* points   = (const float*)d_in[0];
  const float* features = (const float*)d_in[1];
  const float* lift_w   = (const float*)d_in[2];
  const float* lift_b   = (const float*)d_in[3];
  const float* bn_lift_g= (const float*)d_in[4];
  const float* bn_lift_b= (const float*)d_in[5];
  const float* t1_w     = (const float*)d_in[6];
  const float* t1_b     = (const float*)d_in[7];
  const float* bn1_g    = (const float*)d_in[8];
  const float* bn1_b    = (const float*)d_in[9];
  const float* t2_w     = (const float*)d_in[10];
  const float* t2_b     = (const float*)d_in[11];
  const float* bn2_g    = (const float*)d_in[12];
  const float* bn2_b    = (const float*)d_in[13];
  const float* t3_w     = (const float*)d_in[14];
  const float* t3_b     = (const float*)d_in[15];
  const float* bn3_g    = (const float*)d_in[16];
  const float* bn3_b    = (const float*)d_in[17];
  const float* conv_w   = (const float*)d_in[18];
  const float* conv_b   = (const float*)d_in[19];
  const int*   rep_idx  = (const int*)d_in[20];

  char* ws = (char*)d_ws;
  int*    nb   = (int*)   (ws + 0);          // 256 KB
  float*  p    = (float*) (ws + 262144);     // 768 KB
  float*  T    = (float*) (ws + 1048576);    // 4 MB
  float*  Tf   = (float*) (ws + 5242880);    // 20 MB
  float*  wp   = (float*) (ws + 26214400);   // 640 KB
  float*  t1t  = (float*) (ws + 26869760);   // 48 KB
  float*  t2t  = (float*) (ws + 26918912);   // 256 KB
  float*  t3t  = (float*) (ws + 27181056);   // 256 KB
  float*  part = (float*) (ws + 33554432);   // 8 MB (4 splits)
  float4* pts4 = (float4*)(ws + 41943040);   // 256 KB

  float* rep_pos = (float*)d_out;
  float* outp    = (float*)d_out + (size_t)GT*3;

  prep_kernel<<<640, 256, 0, stream>>>(t1_w, t2_w, t3_w, conv_w, points,
                                       t1t, t2t, t3t, wp, pts4);
  knn_kernel<<<GT/8, 256, 0, stream>>>(pts4, rep_idx, nb, p, rep_pos);
  mlp_kernel<<<GT/MG, 256, 0, stream>>>(p, t1t, t1_b, bn1_g, bn1_b,
                                        t2t, t2_b, bn2_g, bn2_b,
                                        t3t, t3_b, bn3_g, bn3_b, T);
  tf_kernel<<<GT/8, 256, 0, stream>>>(T, features, p, nb,
                                      lift_w, lift_b, bn_lift_g, bn_lift_b, Tf);
  dim3 ggrid(GT/32, 4);
  gemm_kernel<<<ggrid, 256, 0, stream>>>(Tf, wp, part);
  reduce_kernel<<<(GT*COUT/4)/256, 256, 0, stream>>>(part, conv_b, outp);
}

// Round 11
// 225.991 us; speedup vs baseline: 1.0747x; 1.0747x over previous
//
#include <hip/hip_runtime.h>
#include <float.h>

#define Bn 2
#define Nn 8192
#define Rr 2048
#define Kk 16
#define CIN 64
#define CL 16
#define COUT 128
#define K2c 256
#define GT (Bn*Rr)      // 4096 groups
#define FD (CL+CIN)     // 80
#define KC (Kk*FD)      // 1280
#define MG 8            // mlp groups per block

// ---------------- prep: weight transposes / permute + pts4 packing ----------------
__global__ __launch_bounds__(256) void prep_kernel(
    const float* __restrict__ t1_w, const float* __restrict__ t2_w,
    const float* __restrict__ t3_w, const float* __restrict__ conv_w,
    const float* __restrict__ points,
    float* __restrict__ t1t, float* __restrict__ t2t,
    float* __restrict__ t3t, float* __restrict__ wp,
    float4* __restrict__ pts4)
{
  int i = blockIdx.x * 256 + threadIdx.x;
  if (i < K2c*48) { int j = i / 48, k = i - j*48; t1t[k*K2c + j] = t1_w[i]; }
  if (i < K2c*K2c) { int j = i >> 8, k = i & 255; t2t[k*K2c + j] = t2_w[i]; t3t[k*K2c + j] = t3_w[i]; }
  if (i < COUT*KC) {
    int o = i / KC, ck = i - o*KC;
    int c = ck >> 4, k = ck & 15;
    wp[(k*FD + c)*COUT + o] = conv_w[i];
  }
  if (i < Bn*Nn) {
    float x = points[i*3+0], y = points[i*3+1], z = points[i*3+2];
    // numpy order: sq = (x*x + y*y) + z*z, muls materialized then summed
    float sq = __fadd_rn(__fadd_rn(__fmul_rn(x,x), __fmul_rn(y,y)), __fmul_rn(z,z));
    pts4[i] = make_float4(x, y, z, sq);
  }
}

// ---------------- knn v5: LDS-chunked two-pass value-scan + tau + collect ----------------
// 512-thread block = 8 waves = 8 queries (1 query/wave — v4 showed halving
// waves hurts latency hiding). Points staged in 3 LDS chunks (48/48/32 KB);
// scan reads ds_read_b128 (low latency) with value-only med3/min top-3.
// tau: 17 f32 wave-min rounds (>= true 17th smallest). Pass 2 re-stages and
// ballot-compacts (d2,m) <= tau with bit-identical d2. Final exact 17-round
// u64 lexicographic extraction = stable top_k semantics.
__global__ __launch_bounds__(512) void knn_kernel(
    const float4* __restrict__ pts4, const int* __restrict__ rep_idx,
    int* __restrict__ nb_idx, float* __restrict__ p_out,
    float* __restrict__ rep_pos_out)
{
  __shared__ float4 ptsS[3072];                    // 48 KB chunk
  __shared__ unsigned long long coll[8][128];      // 8 KB
  int t    = threadIdx.x;
  int lane = t & 63;
  int w    = t >> 6;                 // 0..7
  int g    = blockIdx.x * 8 + w;     // query 0..4095 (8 | 2048: same batch per block)
  int b    = g >> 11;
  int r    = g & 2047;
  int n    = rep_idx[r];
  const float4* pb4 = pts4 + (size_t)b*Nn;
  float4 Q = pb4[n];
  float qx = Q.x, qy = Q.y, qz = Q.z, sqn = Q.w;

  // ---- pass 1: per-lane top-3 VALUES (sorted c0<=c1<=c2) over 3 chunks ----
  float c0 = FLT_MAX, c1 = FLT_MAX, c2 = FLT_MAX;
  for (int c = 0; c < 3; c++) {
    int base  = c * 3072;
    int count = (c < 2) ? 3072 : 2048;
    __syncthreads();
    for (int i = t; i < count; i += 512) ptsS[i] = pb4[base + i];
    __syncthreads();
    int iters = count >> 6;
    #pragma unroll 4
    for (int j = 0; j < iters; j++) {
      float4 P = ptsS[j*64 + lane];
      float dot = __fmaf_rn(qz, P.z, __fmaf_rn(qy, P.y, __fmul_rn(qx, P.x)));
      float d2  = __fsub_rn(__fadd_rn(sqn, P.w), __fmul_rn(2.0f, dot));
      float nc2 = __builtin_amdgcn_fmed3f(c1, c2, d2);
      float nc1 = __builtin_amdgcn_fmed3f(c0, c1, d2);
      float nc0 = fminf(c0, d2);
      c0 = nc0; c1 = nc1; c2 = nc2;
    }
  }

  // ---- tau: 17 rounds of wave-wide f32 min with pop ----
  float tau = FLT_MAX;
  for (int rnd = 0; rnd < 17; rnd++) {
    float m = c0;
    #pragma unroll
    for (int off = 1; off < 64; off <<= 1) m = fminf(m, __shfl_xor(m, off));
    if (c0 == m) { c0 = c1; c1 = c2; c2 = FLT_MAX; }
    tau = m;
  }

  // ---- pass 2: re-stage chunks, collect (d2, m) <= tau, ballot compaction ----
  int cnt = 0;
  for (int c = 0; c < 3; c++) {
    int base  = c * 3072;
    int count = (c < 2) ? 3072 : 2048;
    __syncthreads();   // all waves done reading prev chunk (and pass-1 tail)
    for (int i = t; i < count; i += 512) ptsS[i] = pb4[base + i];
    __syncthreads();
    int iters = count >> 6;
    #pragma unroll 4
    for (int j = 0; j < iters; j++) {
      float4 P = ptsS[j*64 + lane];
      float dot = __fmaf_rn(qz, P.z, __fmaf_rn(qy, P.y, __fmul_rn(qx, P.x)));
      float d2  = __fsub_rn(__fadd_rn(sqn, P.w), __fmul_rn(2.0f, dot));
      bool pr = (d2 <= tau);
      unsigned long long mask = __ballot(pr);
      if (pr) {
        int pos = cnt + (int)__popcll(mask & ((1ull << lane) - 1ull));
        if (pos < 128) {
          unsigned f = __float_as_uint(d2);
          unsigned mono = f ^ ((unsigned)((int)f >> 31) | 0x80000000u);
          coll[w][pos] = ((unsigned long long)mono << 32) | (unsigned)(base + j*64 + lane);
        }
      }
      cnt += (int)__popcll(mask);
    }
  }
  if (cnt > 128) cnt = 128;

  // ---- final: exact top-17 extraction over <=128 unique keys ----
  unsigned long long e1 = (lane < cnt)      ? coll[w][lane]      : ~0ull;
  unsigned long long e2 = (lane + 64 < cnt) ? coll[w][lane + 64] : ~0ull;
  int out_m = 0;
  for (int rnd = 0; rnd < 17; rnd++) {
    unsigned long long myk = (e1 < e2) ? e1 : e2;
    unsigned long long kmin = myk;
    #pragma unroll
    for (int off = 1; off < 64; off <<= 1) {
      unsigned long long o = __shfl_xor(kmin, off);
      kmin = (o < kmin) ? o : kmin;
    }
    if (rnd >= 1 && lane == rnd - 1) out_m = (int)(kmin & 0xFFFFFFFFull);
    if (kmin == e1) e1 = ~0ull;
    else if (kmin == e2) e2 = ~0ull;
  }

  if (lane < 16) {
    nb_idx[g*Kk + lane] = out_m;
    float4 P = pb4[out_m];
    p_out[(g*Kk + lane)*3 + 0] = __fsub_rn(P.x, qx);
    p_out[(g*Kk + lane)*3 + 1] = __fsub_rn(P.y, qy);
    p_out[(g*Kk + lane)*3 + 2] = __fsub_rn(P.z, qz);
  }
  if (lane < 3) rep_pos_out[g*3 + lane] = (lane == 0 ? qx : (lane == 1 ? qy : qz));
}

// ---------------- mlp v4: k-split waves, weights from L2, LDS for broadcasts only ----------------
__device__ __forceinline__ void fma_g(float4& a, float hv, const float4& wv) {
  a.x = fmaf(hv, wv.x, a.x);
  a.y = fmaf(hv, wv.y, a.y);
  a.z = fmaf(hv, wv.z, a.z);
  a.w = fmaf(hv, wv.w, a.w);
}

__global__ __launch_bounds__(256) void mlp_kernel(
    const float* __restrict__ p,
    const float* __restrict__ t1t, const float* __restrict__ t1_b,
    const float* __restrict__ g1v, const float* __restrict__ b1v,
    const float* __restrict__ t2t, const float* __restrict__ t2_b,
    const float* __restrict__ g2v, const float* __restrict__ b2v,
    const float* __restrict__ t3t, const float* __restrict__ t3_b,
    const float* __restrict__ g3v, const float* __restrict__ b3v,
    float* __restrict__ T_out)
{
  __shared__ float pf[48][MG];       // 1.5 KB
  __shared__ float hA[K2c][MG];      // 8 KB
  __shared__ float red[4][64][36];   // 36.9 KB padded partials
  int t = threadIdx.x;
  int w = t >> 6, l = t & 63;
  int g0 = blockIdx.x * MG;
  for (int e = t; e < MG*48; e += 256) {
    int g = e / 48, k = e - g*48;
    pf[k][g] = p[(size_t)(g0+g)*48 + k];
  }
  __syncthreads();

  float4 acc[8];   // acc[g] over cols 4l..4l+3

#define KLOOP(WSRC, KDIM, HBUF)                                        \
  {                                                                    \
    _Pragma("unroll")                                                  \
    for (int q = 0; q < 8; q++) acc[q] = make_float4(0.f,0.f,0.f,0.f); \
    float4 wb0 = *(const float4*)&WSRC[(size_t)w*K2c + 4*l];           \
    float4 wb1 = (w + 4 < KDIM) ?                                      \
        *(const float4*)&WSRC[(size_t)(w+4)*K2c + 4*l] : wb0;          \
    _Pragma("unroll 2")                                                \
    for (int k = w; k < KDIM; k += 4) {                                \
      float4 wc = wb0; wb0 = wb1;                                      \
      if (k + 8 < KDIM)                                                \
        wb1 = *(const float4*)&WSRC[(size_t)(k+8)*K2c + 4*l];          \
      float4 h0 = *(const float4*)&HBUF[k][0];                         \
      float4 h1 = *(const float4*)&HBUF[k][4];                         \
      fma_g(acc[0], h0.x, wc); fma_g(acc[1], h0.y, wc);                \
      fma_g(acc[2], h0.z, wc); fma_g(acc[3], h0.w, wc);                \
      fma_g(acc[4], h1.x, wc); fma_g(acc[5], h1.y, wc);                \
      fma_g(acc[6], h1.z, wc); fma_g(acc[7], h1.w, wc);                \
    }                                                                  \
  }

#define WRITE_RED()                                                        \
  {                                                                        \
    float4 ra, rb;                                                         \
    ra = make_float4(acc[0].x, acc[1].x, acc[2].x, acc[3].x);              \
    rb = make_float4(acc[4].x, acc[5].x, acc[6].x, acc[7].x);              \
    *(float4*)&red[w][l][0]  = ra; *(float4*)&red[w][l][4]  = rb;          \
    ra = make_float4(acc[0].y, acc[1].y, acc[2].y, acc[3].y);              \
    rb = make_float4(acc[4].y, acc[5].y, acc[6].y, acc[7].y);              \
    *(float4*)&red[w][l][8]  = ra; *(float4*)&red[w][l][12] = rb;          \
    ra = make_float4(acc[0].z, acc[1].z, acc[2].z, acc[3].z);              \
    rb = make_float4(acc[4].z, acc[5].z, acc[6].z, acc[7].z);              \
    *(float4*)&red[w][l][16] = ra; *(float4*)&red[w][l][20] = rb;          \
    ra = make_float4(acc[0].w, acc[1].w, acc[2].w, acc[3].w);              \
    rb = make_float4(acc[4].w, acc[5].w, acc[6].w, acc[7].w);              \
    *(float4*)&red[w][l][24] = ra; *(float4*)&red[w][l][28] = rb;          \
  }

#define REDUCE(SA, SB)                                                     \
  float4 SA = make_float4(0.f,0.f,0.f,0.f), SB = SA;                       \
  {                                                                        \
    int lr = t >> 2, cc = t & 3;                                           \
    _Pragma("unroll")                                                      \
    for (int ww = 0; ww < 4; ww++) {                                       \
      float4 pa = *(const float4*)&red[ww][lr][cc*8 + 0];                  \
      float4 pb = *(const float4*)&red[ww][lr][cc*8 + 4];                  \
      SA.x += pa.x; SA.y += pa.y; SA.z += pa.z; SA.w += pa.w;              \
      SB.x += pb.x; SB.y += pb.y; SB.z += pb.z; SB.w += pb.w;              \
    }                                                                      \
  }

  // ===== layer 1 (K=48), relu =====
  KLOOP(t1t, 48, pf)
  WRITE_RED()
  __syncthreads();
  {
    REDUCE(sa, sb)
    float bb = t1_b[t], gg = g1v[t], oo = b1v[t];
    float4 va, vb;
    va.x = fmaxf(fmaf(sa.x + bb, gg, oo), 0.f);
    va.y = fmaxf(fmaf(sa.y + bb, gg, oo), 0.f);
    va.z = fmaxf(fmaf(sa.z + bb, gg, oo), 0.f);
    va.w = fmaxf(fmaf(sa.w + bb, gg, oo), 0.f);
    vb.x = fmaxf(fmaf(sb.x + bb, gg, oo), 0.f);
    vb.y = fmaxf(fmaf(sb.y + bb, gg, oo), 0.f);
    vb.z = fmaxf(fmaf(sb.z + bb, gg, oo), 0.f);
    vb.w = fmaxf(fmaf(sb.w + bb, gg, oo), 0.f);
    *(float4*)&hA[t][0] = va;
    *(float4*)&hA[t][4] = vb;
  }
  __syncthreads();

  // ===== layer 2 (K=256), relu =====
  KLOOP(t2t, K2c, hA)
  __syncthreads();
  WRITE_RED()
  __syncthreads();
  {
    REDUCE(sa, sb)
    float bb = t2_b[t], gg = g2v[t], oo = b2v[t];
    float4 va, vb;
    va.x = fmaxf(fmaf(sa.x + bb, gg, oo), 0.f);
    va.y = fmaxf(fmaf(sa.y + bb, gg, oo), 0.f);
    va.z = fmaxf(fmaf(sa.z + bb, gg, oo), 0.f);
    va.w = fmaxf(fmaf(sa.w + bb, gg, oo), 0.f);
    vb.x = fmaxf(fmaf(sb.x + bb, gg, oo), 0.f);
    vb.y = fmaxf(fmaf(sb.y + bb, gg, oo), 0.f);
    vb.z = fmaxf(fmaf(sb.z + bb, gg, oo), 0.f);
    vb.w = fmaxf(fmaf(sb.w + bb, gg, oo), 0.f);
    *(float4*)&hA[t][0] = va;
    *(float4*)&hA[t][4] = vb;
  }
  __syncthreads();

  // ===== layer 3 (K=256), no relu, to global =====
  KLOOP(t3t, K2c, hA)
  WRITE_RED()
  __syncthreads();
  {
    REDUCE(sa, sb)
    float bb = t3_b[t], gg = g3v[t], oo = b3v[t];
    T_out[(size_t)(g0+0)*K2c + t] = fmaf(sa.x + bb, gg, oo);
    T_out[(size_t)(g0+1)*K2c + t] = fmaf(sa.y + bb, gg, oo);
    T_out[(size_t)(g0+2)*K2c + t] = fmaf(sa.z + bb, gg, oo);
    T_out[(size_t)(g0+3)*K2c + t] = fmaf(sa.w + bb, gg, oo);
    T_out[(size_t)(g0+4)*K2c + t] = fmaf(sb.x + bb, gg, oo);
    T_out[(size_t)(g0+5)*K2c + t] = fmaf(sb.y + bb, gg, oo);
    T_out[(size_t)(g0+6)*K2c + t] = fmaf(sb.z + bb, gg, oo);
    T_out[(size_t)(g0+7)*K2c + t] = fmaf(sb.w + bb, gg, oo);
  }
#undef KLOOP
#undef WRITE_RED
#undef REDUCE
}

// ---------------- tf (fused feat): build feat in LDS, Tf = T @ feat ----------------
__global__ __launch_bounds__(256) void tf_kernel(
    const float* __restrict__ T_in, const float* __restrict__ features,
    const float* __restrict__ p, const int* __restrict__ nb_idx,
    const float* __restrict__ lift_w, const float* __restrict__ lift_b,
    const float* __restrict__ bng, const float* __restrict__ bnb,
    float* __restrict__ Tf)
{
  __shared__ float T_s[8*K2c];    // 8 KB
  __shared__ float f_s[8*KC];     // 40 KB
  __shared__ float ps[8*48];      // 1.5 KB
  __shared__ int   idxs[128];     // 512 B
  __shared__ float lw[48], lb2[16], lg[16], lo[16];
  int t = threadIdx.x;
  int g0 = blockIdx.x * 8;
  int b = g0 / Rr;                // block never straddles batches (2048 % 8 == 0)
  for (int e = t; e < 8*K2c; e += 256) T_s[e] = T_in[(size_t)g0*K2c + e];
  for (int e = t; e < 8*48;  e += 256) ps[e]  = p[(size_t)g0*48 + e];
  if (t < 128) idxs[t] = nb_idx[g0*16 + t];
  if (t >= 128 && t < 176) lw[t-128]  = lift_w[t-128];
  if (t >= 176 && t < 192) lb2[t-176] = lift_b[t-176];
  if (t >= 192 && t < 208) lg[t-192]  = bng[t-192];
  if (t >= 208 && t < 224) lo[t-208]  = bnb[t-208];
  __syncthreads();

  // gather neighbor features: 128 rows of 64, one row per wave-instr
  {
    int wv = t >> 6, ln = t & 63;
    for (int row = wv; row < 128; row += 4) {
      int gg = row >> 4, k = row & 15;
      f_s[gg*KC + k*FD + CL + ln] = features[((size_t)b*Nn + idxs[row])*CIN + ln];
    }
  }
  // lifted BN+ReLU: 8*16*16 = 2048 elements
  for (int e = t; e < 2048; e += 256) {
    int gg = e >> 8, rem = e & 255, k = rem >> 4, c = rem & 15;
    float acc = ps[gg*48 + k*3 + 0]*lw[c*3+0] + ps[gg*48 + k*3 + 1]*lw[c*3+1]
              + ps[gg*48 + k*3 + 2]*lw[c*3+2] + lb2[c];
    acc = acc*lg[c] + lo[c];
    f_s[gg*KC + k*FD + c] = fmaxf(acc, 0.f);
  }
  __syncthreads();

  int gg = t >> 5;
  int cl = t & 31;
  for (int ci = cl; ci < FD; ci += 32) {
    float fcol[16];
    #pragma unroll
    for (int j = 0; j < 16; j++) fcol[j] = f_s[gg*KC + j*FD + ci];
    #pragma unroll
    for (int k = 0; k < 16; k++) {
      float acc = 0.f;
      #pragma unroll
      for (int j = 0; j < 16; j++) acc = fmaf(T_s[gg*K2c + k*16 + j], fcol[j], acc);
      Tf[(size_t)(g0+gg)*KC + k*FD + ci] = acc;
    }
  }
}

// ---------------- gemm: out = Tf(4096x1280) @ Wp(1280x128), split-K=4 ----------------
__global__ __launch_bounds__(256) void gemm_kernel(
    const float* __restrict__ A,    // Tf
    const float* __restrict__ Bm,   // Wp
    float* __restrict__ part)       // [4][GT][COUT]
{
  __shared__ float As[16*36];
  __shared__ float Bs[16*COUT];
  int t = threadIdx.x;
  int m0 = blockIdx.x * 32;
  int ky = blockIdx.y;
  int kbase0 = ky * (KC/4);
  float acc[4][4];
  #pragma unroll
  for (int i = 0; i < 4; i++)
    #pragma unroll
    for (int j = 0; j < 4; j++) acc[i][j] = 0.f;
  int tn = t & 31, tm = t >> 5;

  for (int kt = 0; kt < KC/4; kt += 16) {
    int kb = kbase0 + kt;
    {
      int kcol = t & 15, row = t >> 4;
      As[kcol*36 + row]      = A[(size_t)(m0+row)*KC + kb + kcol];
      As[kcol*36 + row + 16] = A[(size_t)(m0+row+16)*KC + kb + kcol];
    }
    {
      int o = t & 127, kk2 = t >> 7;
      #pragma unroll
      for (int p4 = 0; p4 < 8; p4++) {
        int kk = kk2 + p4*2;
        Bs[kk*COUT + o] = Bm[(size_t)(kb+kk)*COUT + o];
      }
    }
    __syncthreads();
    #pragma unroll
    for (int kk = 0; kk < 16; kk++) {
      float4 a4 = *(const float4*)&As[kk*36 + tm*4];
      float4 b4 = *(const float4*)&Bs[kk*COUT + tn*4];
      float av[4] = {a4.x, a4.y, a4.z, a4.w};
      float bv[4] = {b4.x, b4.y, b4.z, b4.w};
      #pragma unroll
      for (int i = 0; i < 4; i++)
        #pragma unroll
        for (int j = 0; j < 4; j++) acc[i][j] = fmaf(av[i], bv[j], acc[i][j]);
    }
    __syncthreads();
  }
  #pragma unroll
  for (int i = 0; i < 4; i++) {
    float4 v = make_float4(acc[i][0], acc[i][1], acc[i][2], acc[i][3]);
    *(float4*)&part[((size_t)ky*GT + m0 + tm*4 + i)*COUT + tn*4] = v;
  }
}

// ---------------- reduce: out = sum(part[0..3]) + bias ----------------
__global__ __launch_bounds__(256) void reduce_kernel(
    const float* __restrict__ part, const float* __restrict__ conv_b,
    float* __restrict__ outp)
{
  int i = blockIdx.x*256 + threadIdx.x;
  const float4* p0 = (const float4*)part;
  const float4* p1 = (const float4*)(part + 1*(size_t)GT*COUT);
  const float4* p2 = (const float4*)(part + 2*(size_t)GT*COUT);
  const float4* p3 = (const float4*)(part + 3*(size_t)GT*COUT);
  float4 a = p0[i], b = p1[i], c = p2[i], d = p3[i];
  float4 e = ((const float4*)conv_b)[i & 31];
  float4 rr;
  rr.x = a.x + b.x + c.x + d.x + e.x;
  rr.y = a.y + b.y + c.y + d.y + e.y;
  rr.z = a.z + b.z + c.z + d.z + e.z;
  rr.w = a.w + b.w + c.w + d.w + e.w;
  ((float4*)outp)[i] = rr;
}

extern "C" void kernel_launch(void* const* d_in, const int* in_sizes, int n_in,
                              void* d_out, int out_size, void* d_ws, size_t ws_size,
                              hipStream_t stream) {
  const float* points   = (const float*)d_in[0];
  const float* features = (const float*)d_in[1];
  const float* lift_w   = (const float*)d_in[2];
  const float* lift_b   = (const float*)d_in[3];
  const float* bn_lift_g= (const float*)d_in[4];
  const float* bn_lift_b= (const float*)d_in[5];
  const float* t1_w     = (const float*)d_in[6];
  const float* t1_b     = (const float*)d_in[7];
  const float* bn1_g    = (const float*)d_in[8];
  const float* bn1_b    = (const float*)d_in[9];
  const float* t2_w     = (const float*)d_in[10];
  const float* t2_b     = (const float*)d_in[11];
  const float* bn2_g    = (const float*)d_in[12];
  const float* bn2_b    = (const float*)d_in[13];
  const float* t3_w     = (const float*)d_in[14];
  const float* t3_b     = (const float*)d_in[15];
  const float* bn3_g    = (const float*)d_in[16];
  const float* bn3_b    = (const float*)d_in[17];
  const float* conv_w   = (const float*)d_in[18];
  const float* conv_b   = (const float*)d_in[19];
  const int*   rep_idx  = (const int*)d_in[20];

  char* ws = (char*)d_ws;
  int*    nb   = (int*)   (ws + 0);          // 256 KB
  float*  p    = (float*) (ws + 262144);     // 768 KB
  float*  T    = (float*) (ws + 1048576);    // 4 MB
  float*  Tf   = (float*) (ws + 5242880);    // 20 MB
  float*  wp   = (float*) (ws + 26214400);   // 640 KB
  float*  t1t  = (float*) (ws + 26869760);   // 48 KB
  float*  t2t  = (float*) (ws + 26918912);   // 256 KB
  float*  t3t  = (float*) (ws + 27181056);   // 256 KB
  float*  part = (float*) (ws + 33554432);   // 8 MB (4 splits)
  float4* pts4 = (float4*)(ws + 41943040);   // 256 KB

  float* rep_pos = (float*)d_out;
  float* outp    = (float*)d_out + (size_t)GT*3;

  prep_kernel<<<640, 256, 0, stream>>>(t1_w, t2_w, t3_w, conv_w, points,
                                       t1t, t2t, t3t, wp, pts4);
  knn_kernel<<<GT/8, 512, 0, stream>>>(pts4, rep_idx, nb, p, rep_pos);
  mlp_kernel<<<GT/MG, 256, 0, stream>>>(p, t1t, t1_b, bn1_g, bn1_b,
                                        t2t, t2_b, bn2_g, bn2_b,
                                        t3t, t3_b, bn3_g, bn3_b, T);
  tf_kernel<<<GT/8, 256, 0, stream>>>(T, features, p, nb,
                                      lift_w, lift_b, bn_lift_g, bn_lift_b, Tf);
  dim3 ggrid(GT/32, 4);
  gemm_kernel<<<ggrid, 256, 0, stream>>>(Tf, wp, part);
  reduce_kernel<<<(GT*COUT/4)/256, 256, 0, stream>>>(part, conv_b, outp);
}

// Round 12
// 224.866 us; speedup vs baseline: 1.0800x; 1.0050x over previous
//
#include <hip/hip_runtime.h>
#include <float.h>

#define Bn 2
#define Nn 8192
#define Rr 2048
#define Kk 16
#define CIN 64
#define CL 16
#define COUT 128
#define K2c 256
#define GT (Bn*Rr)      // 4096 groups
#define FD (CL+CIN)     // 80
#define KC (Kk*FD)      // 1280
#define MG 8            // mlp groups per block

// ---------------- prep: weight transposes / permute + pts4 packing ----------------
__global__ __launch_bounds__(256) void prep_kernel(
    const float* __restrict__ t1_w, const float* __restrict__ t2_w,
    const float* __restrict__ t3_w, const float* __restrict__ conv_w,
    const float* __restrict__ points,
    float* __restrict__ t1t, float* __restrict__ t2t,
    float* __restrict__ t3t, float* __restrict__ wp,
    float4* __restrict__ pts4)
{
  int i = blockIdx.x * 256 + threadIdx.x;
  if (i < K2c*48) { int j = i / 48, k = i - j*48; t1t[k*K2c + j] = t1_w[i]; }
  if (i < K2c*K2c) { int j = i >> 8, k = i & 255; t2t[k*K2c + j] = t2_w[i]; t3t[k*K2c + j] = t3_w[i]; }
  if (i < COUT*KC) {
    int o = i / KC, ck = i - o*KC;
    int c = ck >> 4, k = ck & 15;
    wp[(k*FD + c)*COUT + o] = conv_w[i];
  }
  if (i < Bn*Nn) {
    float x = points[i*3+0], y = points[i*3+1], z = points[i*3+2];
    // numpy order: sq = (x*x + y*y) + z*z, muls materialized then summed
    float sq = __fadd_rn(__fadd_rn(__fmul_rn(x,x), __fmul_rn(y,y)), __fmul_rn(z,z));
    pts4[i] = make_float4(x, y, z, sq);
  }
}

// ---------------- knn v6: LDS-chunked two-pass, 16 waves/block = max occupancy ----------------
// 1024-thread block = 16 waves = 16 queries (1 query/wave). Points staged in
// 3 LDS chunks (48/48/32 KB) shared by all 16 waves; 64 KB LDS total ->
// 2 blocks/CU = 32 waves/CU (hardware max) for pipe overlap. Value-only
// med3/min top-3 scan; tau = 17 f32 wave-min rounds (>= true 17th smallest);
// pass 2 re-stages and ballot-compacts (d2,m) <= tau with bit-identical d2;
// final exact 17-round u64 lexicographic extraction = stable top_k semantics.
__global__ __launch_bounds__(1024) void knn_kernel(
    const float4* __restrict__ pts4, const int* __restrict__ rep_idx,
    int* __restrict__ nb_idx, float* __restrict__ p_out,
    float* __restrict__ rep_pos_out)
{
  __shared__ float4 ptsS[3072];                    // 48 KB chunk
  __shared__ unsigned long long coll[16][128];     // 16 KB
  int t    = threadIdx.x;
  int lane = t & 63;
  int w    = t >> 6;                  // 0..15
  int g    = blockIdx.x * 16 + w;     // query 0..4095 (16 | 2048: same batch per block)
  int b    = g >> 11;
  int r    = g & 2047;
  int n    = rep_idx[r];
  const float4* pb4 = pts4 + (size_t)b*Nn;
  float4 Q = pb4[n];
  float qx = Q.x, qy = Q.y, qz = Q.z, sqn = Q.w;

  // ---- pass 1: per-lane top-3 VALUES (sorted c0<=c1<=c2) over 3 chunks ----
  float c0 = FLT_MAX, c1 = FLT_MAX, c2 = FLT_MAX;
  for (int c = 0; c < 3; c++) {
    int base  = c * 3072;
    int count = (c < 2) ? 3072 : 2048;
    __syncthreads();
    for (int i = t; i < count; i += 1024) ptsS[i] = pb4[base + i];
    __syncthreads();
    int iters = count >> 6;
    #pragma unroll 4
    for (int j = 0; j < iters; j++) {
      float4 P = ptsS[j*64 + lane];
      float dot = __fmaf_rn(qz, P.z, __fmaf_rn(qy, P.y, __fmul_rn(qx, P.x)));
      float d2  = __fsub_rn(__fadd_rn(sqn, P.w), __fmul_rn(2.0f, dot));
      float nc2 = __builtin_amdgcn_fmed3f(c1, c2, d2);
      float nc1 = __builtin_amdgcn_fmed3f(c0, c1, d2);
      float nc0 = fminf(c0, d2);
      c0 = nc0; c1 = nc1; c2 = nc2;
    }
  }

  // ---- tau: 17 rounds of wave-wide f32 min with pop ----
  float tau = FLT_MAX;
  for (int rnd = 0; rnd < 17; rnd++) {
    float m = c0;
    #pragma unroll
    for (int off = 1; off < 64; off <<= 1) m = fminf(m, __shfl_xor(m, off));
    if (c0 == m) { c0 = c1; c1 = c2; c2 = FLT_MAX; }
    tau = m;
  }

  // ---- pass 2: re-stage chunks, collect (d2, m) <= tau, ballot compaction ----
  int cnt = 0;
  for (int c = 0; c < 3; c++) {
    int base  = c * 3072;
    int count = (c < 2) ? 3072 : 2048;
    __syncthreads();   // all waves done reading prev chunk (and pass-1 tail)
    for (int i = t; i < count; i += 1024) ptsS[i] = pb4[base + i];
    __syncthreads();
    int iters = count >> 6;
    #pragma unroll 4
    for (int j = 0; j < iters; j++) {
      float4 P = ptsS[j*64 + lane];
      float dot = __fmaf_rn(qz, P.z, __fmaf_rn(qy, P.y, __fmul_rn(qx, P.x)));
      float d2  = __fsub_rn(__fadd_rn(sqn, P.w), __fmul_rn(2.0f, dot));
      bool pr = (d2 <= tau);
      unsigned long long mask = __ballot(pr);
      if (pr) {
        int pos = cnt + (int)__popcll(mask & ((1ull << lane) - 1ull));
        if (pos < 128) {
          unsigned f = __float_as_uint(d2);
          unsigned mono = f ^ ((unsigned)((int)f >> 31) | 0x80000000u);
          coll[w][pos] = ((unsigned long long)mono << 32) | (unsigned)(base + j*64 + lane);
        }
      }
      cnt += (int)__popcll(mask);
    }
  }
  if (cnt > 128) cnt = 128;

  // ---- final: exact top-17 extraction over <=128 unique keys ----
  unsigned long long e1 = (lane < cnt)      ? coll[w][lane]      : ~0ull;
  unsigned long long e2 = (lane + 64 < cnt) ? coll[w][lane + 64] : ~0ull;
  int out_m = 0;
  for (int rnd = 0; rnd < 17; rnd++) {
    unsigned long long myk = (e1 < e2) ? e1 : e2;
    unsigned long long kmin = myk;
    #pragma unroll
    for (int off = 1; off < 64; off <<= 1) {
      unsigned long long o = __shfl_xor(kmin, off);
      kmin = (o < kmin) ? o : kmin;
    }
    if (rnd >= 1 && lane == rnd - 1) out_m = (int)(kmin & 0xFFFFFFFFull);
    if (kmin == e1) e1 = ~0ull;
    else if (kmin == e2) e2 = ~0ull;
  }

  if (lane < 16) {
    nb_idx[g*Kk + lane] = out_m;
    float4 P = pb4[out_m];
    p_out[(g*Kk + lane)*3 + 0] = __fsub_rn(P.x, qx);
    p_out[(g*Kk + lane)*3 + 1] = __fsub_rn(P.y, qy);
    p_out[(g*Kk + lane)*3 + 2] = __fsub_rn(P.z, qz);
  }
  if (lane < 3) rep_pos_out[g*3 + lane] = (lane == 0 ? qx : (lane == 1 ? qy : qz));
}

// ---------------- mlp v4: k-split waves, weights from L2, LDS for broadcasts only ----------------
__device__ __forceinline__ void fma_g(float4& a, float hv, const float4& wv) {
  a.x = fmaf(hv, wv.x, a.x);
  a.y = fmaf(hv, wv.y, a.y);
  a.z = fmaf(hv, wv.z, a.z);
  a.w = fmaf(hv, wv.w, a.w);
}

__global__ __launch_bounds__(256) void mlp_kernel(
    const float* __restrict__ p,
    const float* __restrict__ t1t, const float* __restrict__ t1_b,
    const float* __restrict__ g1v, const float* __restrict__ b1v,
    const float* __restrict__ t2t, const float* __restrict__ t2_b,
    const float* __restrict__ g2v, const float* __restrict__ b2v,
    const float* __restrict__ t3t, const float* __restrict__ t3_b,
    const float* __restrict__ g3v, const float* __restrict__ b3v,
    float* __restrict__ T_out)
{
  __shared__ float pf[48][MG];       // 1.5 KB
  __shared__ float hA[K2c][MG];      // 8 KB
  __shared__ float red[4][64][36];   // 36.9 KB padded partials
  int t = threadIdx.x;
  int w = t >> 6, l = t & 63;
  int g0 = blockIdx.x * MG;
  for (int e = t; e < MG*48; e += 256) {
    int g = e / 48, k = e - g*48;
    pf[k][g] = p[(size_t)(g0+g)*48 + k];
  }
  __syncthreads();

  float4 acc[8];   // acc[g] over cols 4l..4l+3

#define KLOOP(WSRC, KDIM, HBUF)                                        \
  {                                                                    \
    _Pragma("unroll")                                                  \
    for (int q = 0; q < 8; q++) acc[q] = make_float4(0.f,0.f,0.f,0.f); \
    float4 wb0 = *(const float4*)&WSRC[(size_t)w*K2c + 4*l];           \
    float4 wb1 = (w + 4 < KDIM) ?                                      \
        *(const float4*)&WSRC[(size_t)(w+4)*K2c + 4*l] : wb0;          \
    _Pragma("unroll 2")                                                \
    for (int k = w; k < KDIM; k += 4) {                                \
      float4 wc = wb0; wb0 = wb1;                                      \
      if (k + 8 < KDIM)                                                \
        wb1 = *(const float4*)&WSRC[(size_t)(k+8)*K2c + 4*l];          \
      float4 h0 = *(const float4*)&HBUF[k][0];                         \
      float4 h1 = *(const float4*)&HBUF[k][4];                         \
      fma_g(acc[0], h0.x, wc); fma_g(acc[1], h0.y, wc);                \
      fma_g(acc[2], h0.z, wc); fma_g(acc[3], h0.w, wc);                \
      fma_g(acc[4], h1.x, wc); fma_g(acc[5], h1.y, wc);                \
      fma_g(acc[6], h1.z, wc); fma_g(acc[7], h1.w, wc);                \
    }                                                                  \
  }

#define WRITE_RED()                                                        \
  {                                                                        \
    float4 ra, rb;                                                         \
    ra = make_float4(acc[0].x, acc[1].x, acc[2].x, acc[3].x);              \
    rb = make_float4(acc[4].x, acc[5].x, acc[6].x, acc[7].x);              \
    *(float4*)&red[w][l][0]  = ra; *(float4*)&red[w][l][4]  = rb;          \
    ra = make_float4(acc[0].y, acc[1].y, acc[2].y, acc[3].y);              \
    rb = make_float4(acc[4].y, acc[5].y, acc[6].y, acc[7].y);              \
    *(float4*)&red[w][l][8]  = ra; *(float4*)&red[w][l][12] = rb;          \
    ra = make_float4(acc[0].z, acc[1].z, acc[2].z, acc[3].z);              \
    rb = make_float4(acc[4].z, acc[5].z, acc[6].z, acc[7].z);              \
    *(float4*)&red[w][l][16] = ra; *(float4*)&red[w][l][20] = rb;          \
    ra = make_float4(acc[0].w, acc[1].w, acc[2].w, acc[3].w);              \
    rb = make_float4(acc[4].w, acc[5].w, acc[6].w, acc[7].w);              \
    *(float4*)&red[w][l][24] = ra; *(float4*)&red[w][l][28] = rb;          \
  }

#define REDUCE(SA, SB)                                                     \
  float4 SA = make_float4(0.f,0.f,0.f,0.f), SB = SA;                       \
  {                                                                        \
    int lr = t >> 2, cc = t & 3;                                           \
    _Pragma("unroll")                                                      \
    for (int ww = 0; ww < 4; ww++) {                                       \
      float4 pa = *(const float4*)&red[ww][lr][cc*8 + 0];                  \
      float4 pb = *(const float4*)&red[ww][lr][cc*8 + 4];                  \
      SA.x += pa.x; SA.y += pa.y; SA.z += pa.z; SA.w += pa.w;              \
      SB.x += pb.x; SB.y += pb.y; SB.z += pb.z; SB.w += pb.w;              \
    }                                                                      \
  }

  // ===== layer 1 (K=48), relu =====
  KLOOP(t1t, 48, pf)
  WRITE_RED()
  __syncthreads();
  {
    REDUCE(sa, sb)
    float bb = t1_b[t], gg = g1v[t], oo = b1v[t];
    float4 va, vb;
    va.x = fmaxf(fmaf(sa.x + bb, gg, oo), 0.f);
    va.y = fmaxf(fmaf(sa.y + bb, gg, oo), 0.f);
    va.z = fmaxf(fmaf(sa.z + bb, gg, oo), 0.f);
    va.w = fmaxf(fmaf(sa.w + bb, gg, oo), 0.f);
    vb.x = fmaxf(fmaf(sb.x + bb, gg, oo), 0.f);
    vb.y = fmaxf(fmaf(sb.y + bb, gg, oo), 0.f);
    vb.z = fmaxf(fmaf(sb.z + bb, gg, oo), 0.f);
    vb.w = fmaxf(fmaf(sb.w + bb, gg, oo), 0.f);
    *(float4*)&hA[t][0] = va;
    *(float4*)&hA[t][4] = vb;
  }
  __syncthreads();

  // ===== layer 2 (K=256), relu =====
  KLOOP(t2t, K2c, hA)
  __syncthreads();
  WRITE_RED()
  __syncthreads();
  {
    REDUCE(sa, sb)
    float bb = t2_b[t], gg = g2v[t], oo = b2v[t];
    float4 va, vb;
    va.x = fmaxf(fmaf(sa.x + bb, gg, oo), 0.f);
    va.y = fmaxf(fmaf(sa.y + bb, gg, oo), 0.f);
    va.z = fmaxf(fmaf(sa.z + bb, gg, oo), 0.f);
    va.w = fmaxf(fmaf(sa.w + bb, gg, oo), 0.f);
    vb.x = fmaxf(fmaf(sb.x + bb, gg, oo), 0.f);
    vb.y = fmaxf(fmaf(sb.y + bb, gg, oo), 0.f);
    vb.z = fmaxf(fmaf(sb.z + bb, gg, oo), 0.f);
    vb.w = fmaxf(fmaf(sb.w + bb, gg, oo), 0.f);
    *(float4*)&hA[t][0] = va;
    *(float4*)&hA[t][4] = vb;
  }
  __syncthreads();

  // ===== layer 3 (K=256), no relu, to global =====
  KLOOP(t3t, K2c, hA)
  WRITE_RED()
  __syncthreads();
  {
    REDUCE(sa, sb)
    float bb = t3_b[t], gg = g3v[t], oo = b3v[t];
    T_out[(size_t)(g0+0)*K2c + t] = fmaf(sa.x + bb, gg, oo);
    T_out[(size_t)(g0+1)*K2c + t] = fmaf(sa.y + bb, gg, oo);
    T_out[(size_t)(g0+2)*K2c + t] = fmaf(sa.z + bb, gg, oo);
    T_out[(size_t)(g0+3)*K2c + t] = fmaf(sa.w + bb, gg, oo);
    T_out[(size_t)(g0+4)*K2c + t] = fmaf(sb.x + bb, gg, oo);
    T_out[(size_t)(g0+5)*K2c + t] = fmaf(sb.y + bb, gg, oo);
    T_out[(size_t)(g0+6)*K2c + t] = fmaf(sb.z + bb, gg, oo);
    T_out[(size_t)(g0+7)*K2c + t] = fmaf(sb.w + bb, gg, oo);
  }
#undef KLOOP
#undef WRITE_RED
#undef REDUCE
}

// ---------------- tf (fused feat): build feat in LDS, Tf = T @ feat ----------------
__global__ __launch_bounds__(256) void tf_kernel(
    const float* __restrict__ T_in, const float* __restrict__ features,
    const float* __restrict__ p, const int* __restrict__ nb_idx,
    const float* __restrict__ lift_w, const float* __restrict__ lift_b,
    const float* __restrict__ bng, const float* __restrict__ bnb,
    float* __restrict__ Tf)
{
  __shared__ float T_s[8*K2c];    // 8 KB
  __shared__ float f_s[8*KC];     // 40 KB
  __shared__ float ps[8*48];      // 1.5 KB
  __shared__ int   idxs[128];     // 512 B
  __shared__ float lw[48], lb2[16], lg[16], lo[16];
  int t = threadIdx.x;
  int g0 = blockIdx.x * 8;
  int b = g0 / Rr;                // block never straddles batches (2048 % 8 == 0)
  for (int e = t; e < 8*K2c; e += 256) T_s[e] = T_in[(size_t)g0*K2c + e];
  for (int e = t; e < 8*48;  e += 256) ps[e]  = p[(size_t)g0*48 + e];
  if (t < 128) idxs[t] = nb_idx[g0*16 + t];
  if (t >= 128 && t < 176) lw[t-128]  = lift_w[t-128];
  if (t >= 176 && t < 192) lb2[t-176] = lift_b[t-176];
  if (t >= 192 && t < 208) lg[t-192]  = bng[t-192];
  if (t >= 208 && t < 224) lo[t-208]  = bnb[t-208];
  __syncthreads();

  // gather neighbor features: 128 rows of 64, one row per wave-instr
  {
    int wv = t >> 6, ln = t & 63;
    for (int row = wv; row < 128; row += 4) {
      int gg = row >> 4, k = row & 15;
      f_s[gg*KC + k*FD + CL + ln] = features[((size_t)b*Nn + idxs[row])*CIN + ln];
    }
  }
  // lifted BN+ReLU: 8*16*16 = 2048 elements
  for (int e = t; e < 2048; e += 256) {
    int gg = e >> 8, rem = e & 255, k = rem >> 4, c = rem & 15;
    float acc = ps[gg*48 + k*3 + 0]*lw[c*3+0] + ps[gg*48 + k*3 + 1]*lw[c*3+1]
              + ps[gg*48 + k*3 + 2]*lw[c*3+2] + lb2[c];
    acc = acc*lg[c] + lo[c];
    f_s[gg*KC + k*FD + c] = fmaxf(acc, 0.f);
  }
  __syncthreads();

  int gg = t >> 5;
  int cl = t & 31;
  for (int ci = cl; ci < FD; ci += 32) {
    float fcol[16];
    #pragma unroll
    for (int j = 0; j < 16; j++) fcol[j] = f_s[gg*KC + j*FD + ci];
    #pragma unroll
    for (int k = 0; k < 16; k++) {
      float acc = 0.f;
      #pragma unroll
      for (int j = 0; j < 16; j++) acc = fmaf(T_s[gg*K2c + k*16 + j], fcol[j], acc);
      Tf[(size_t)(g0+gg)*KC + k*FD + ci] = acc;
    }
  }
}

// ---------------- gemm: out = Tf(4096x1280) @ Wp(1280x128), split-K=4 ----------------
__global__ __launch_bounds__(256) void gemm_kernel(
    const float* __restrict__ A,    // Tf
    const float* __restrict__ Bm,   // Wp
    float* __restrict__ part)       // [4][GT][COUT]
{
  __shared__ float As[16*36];
  __shared__ float Bs[16*COUT];
  int t = threadIdx.x;
  int m0 = blockIdx.x * 32;
  int ky = blockIdx.y;
  int kbase0 = ky * (KC/4);
  float acc[4][4];
  #pragma unroll
  for (int i = 0; i < 4; i++)
    #pragma unroll
    for (int j = 0; j < 4; j++) acc[i][j] = 0.f;
  int tn = t & 31, tm = t >> 5;

  for (int kt = 0; kt < KC/4; kt += 16) {
    int kb = kbase0 + kt;
    {
      int kcol = t & 15, row = t >> 4;
      As[kcol*36 + row]      = A[(size_t)(m0+row)*KC + kb + kcol];
      As[kcol*36 + row + 16] = A[(size_t)(m0+row+16)*KC + kb + kcol];
    }
    {
      int o = t & 127, kk2 = t >> 7;
      #pragma unroll
      for (int p4 = 0; p4 < 8; p4++) {
        int kk = kk2 + p4*2;
        Bs[kk*COUT + o] = Bm[(size_t)(kb+kk)*COUT + o];
      }
    }
    __syncthreads();
    #pragma unroll
    for (int kk = 0; kk < 16; kk++) {
      float4 a4 = *(const float4*)&As[kk*36 + tm*4];
      float4 b4 = *(const float4*)&Bs[kk*COUT + tn*4];
      float av[4] = {a4.x, a4.y, a4.z, a4.w};
      float bv[4] = {b4.x, b4.y, b4.z, b4.w};
      #pragma unroll
      for (int i = 0; i < 4; i++)
        #pragma unroll
        for (int j = 0; j < 4; j++) acc[i][j] = fmaf(av[i], bv[j], acc[i][j]);
    }
    __syncthreads();
  }
  #pragma unroll
  for (int i = 0; i < 4; i++) {
    float4 v = make_float4(acc[i][0], acc[i][1], acc[i][2], acc[i][3]);
    *(float4*)&part[((size_t)ky*GT + m0 + tm*4 + i)*COUT + tn*4] = v;
  }
}

// ---------------- reduce: out = sum(part[0..3]) + bias ----------------
__global__ __launch_bounds__(256) void reduce_kernel(
    const float* __restrict__ part, const float* __restrict__ conv_b,
    float* __restrict__ outp)
{
  int i = blockIdx.x*256 + threadIdx.x;
  const float4* p0 = (const float4*)part;
  const float4* p1 = (const float4*)(part + 1*(size_t)GT*COUT);
  const float4* p2 = (const float4*)(part + 2*(size_t)GT*COUT);
  const float4* p3 = (const float4*)(part + 3*(size_t)GT*COUT);
  float4 a = p0[i], b = p1[i], c = p2[i], d = p3[i];
  float4 e = ((const float4*)conv_b)[i & 31];
  float4 rr;
  rr.x = a.x + b.x + c.x + d.x + e.x;
  rr.y = a.y + b.y + c.y + d.y + e.y;
  rr.z = a.z + b.z + c.z + d.z + e.z;
  rr.w = a.w + b.w + c.w + d.w + e.w;
  ((float4*)outp)[i] = rr;
}

extern "C" void kernel_launch(void* const* d_in, const int* in_sizes, int n_in,
                              void* d_out, int out_size, void* d_ws, size_t ws_size,
                              hipStream_t stream) {
  const float* points   = (const float*)d_in[0];
  const float* features = (const float*)d_in[1];
  const float* lift_w   = (const float*)d_in[2];
  const float* lift_b   = (const float*)d_in[3];
  const float* bn_lift_g= (const float*)d_in[4];
  const float* bn_lift_b= (const float*)d_in[5];
  const float* t1_w     = (const float*)d_in[6];
  const float* t1_b     = (const float*)d_in[7];
  const float* bn1_g    = (const float*)d_in[8];
  const float* bn1_b    = (const float*)d_in[9];
  const float* t2_w     = (const float*)d_in[10];
  const float* t2_b     = (const float*)d_in[11];
  const float* bn2_g    = (const float*)d_in[12];
  const float* bn2_b    = (const float*)d_in[13];
  const float* t3_w     = (const float*)d_in[14];
  const float* t3_b     = (const float*)d_in[15];
  const float* bn3_g    = (const float*)d_in[16];
  const float* bn3_b    = (const float*)d_in[17];
  const float* conv_w   = (const float*)d_in[18];
  const float* conv_b   = (const float*)d_in[19];
  const int*   rep_idx  = (const int*)d_in[20];

  char* ws = (char*)d_ws;
  int*    nb   = (int*)   (ws + 0);          // 256 KB
  float*  p    = (float*) (ws + 262144);     // 768 KB
  float*  T    = (float*) (ws + 1048576);    // 4 MB
  float*  Tf   = (float*) (ws + 5242880);    // 20 MB
  float*  wp   = (float*) (ws + 26214400);   // 640 KB
  float*  t1t  = (float*) (ws + 26869760);   // 48 KB
  float*  t2t  = (float*) (ws + 26918912);   // 256 KB
  float*  t3t  = (float*) (ws + 27181056);   // 256 KB
  float*  part = (float*) (ws + 33554432);   // 8 MB (4 splits)
  float4* pts4 = (float4*)(ws + 41943040);   // 256 KB

  float* rep_pos = (float*)d_out;
  float* outp    = (float*)d_out + (size_t)GT*3;

  prep_kernel<<<640, 256, 0, stream>>>(t1_w, t2_w, t3_w, conv_w, points,
                                       t1t, t2t, t3t, wp, pts4);
  knn_kernel<<<GT/16, 1024, 0, stream>>>(pts4, rep_idx, nb, p, rep_pos);
  mlp_kernel<<<GT/MG, 256, 0, stream>>>(p, t1t, t1_b, bn1_g, bn1_b,
                                        t2t, t2_b, bn2_g, bn2_b,
                                        t3t, t3_b, bn3_g, bn3_b, T);
  tf_kernel<<<GT/8, 256, 0, stream>>>(T, features, p, nb,
                                      lift_w, lift_b, bn_lift_g, bn_lift_b, Tf);
  dim3 ggrid(GT/32, 4);
  gemm_kernel<<<ggrid, 256, 0, stream>>>(Tf, wp, part);
  reduce_kernel<<<(GT*COUT/4)/256, 256, 0, stream>>>(part, conv_b, outp);
}